// Round 13
// baseline (317.690 us; speedup 1.0000x reference)
//
#include <hip/hip_runtime.h>

#define D 16
#define EFD 8
#define NREP 64       // BN-stats replica buffers (breaks atomic same-line contention)
#define TSTRIDE 276   // Tt node stride: 4*276%32==16 -> quad writes land on disjoint half-banks (<=2-way, free)

typedef unsigned short u16;
typedef unsigned int u32;
typedef __attribute__((ext_vector_type(8))) short short8;  // 8 bf16 = 4 VGPRs (MFMA A/B frag)
typedef __attribute__((ext_vector_type(4))) float f32x4;   // MFMA C/D frag

__device__ __forceinline__ u16 f2bf(float x) {          // round-to-nearest-even
    u32 u = __float_as_uint(x);
    u += 0x7fffu + ((u >> 16) & 1u);
    return (u16)(u >> 16);
}
__device__ __forceinline__ void unpack8(uint4 u, float* f) {
    f[0] = __uint_as_float(u.x << 16); f[1] = __uint_as_float(u.x & 0xffff0000u);
    f[2] = __uint_as_float(u.y << 16); f[3] = __uint_as_float(u.y & 0xffff0000u);
    f[4] = __uint_as_float(u.z << 16); f[5] = __uint_as_float(u.z & 0xffff0000u);
    f[6] = __uint_as_float(u.w << 16); f[7] = __uint_as_float(u.w & 0xffff0000u);
}

// ---------------- zero scratch ----------------

__global__ void k_zero2(int* a, int na, float* b, int nb) {
    int i = blockIdx.x * 256 + threadIdx.x;
    if (i < na) a[i] = 0;
    if (i < nb) b[i] = 0.f;
}

// ---------------- rank: one atomic per edge per side ----------------

__global__ void k_rank2(const int* __restrict__ src, const int* __restrict__ dst,
                        int* __restrict__ cntS, int* __restrict__ cntD,
                        int* __restrict__ rankS, int* __restrict__ rankD, int E_) {
    int e = blockIdx.x * 256 + threadIdx.x;
    if (e < E_) {
        rankS[e] = atomicAdd(&cntS[src[e]], 1);
        rankD[e] = atomicAdd(&cntD[dst[e]], 1);
    }
}

// ---------------- scans over cntS|cntD ----------------

__global__ void k_scanA2(const int* __restrict__ cnt2, int* __restrict__ offs2,
                         int* __restrict__ bsum2, int n, int nScan) {
    __shared__ int s[1024];
    int half = blockIdx.x / nScan;
    int blk  = blockIdx.x % nScan;
    const int* c = cnt2 + (size_t)half * n;
    int* of = offs2 + (size_t)half * (n + 1);
    int* bs = bsum2 + half * 64;
    int i = blk * 1024 + threadIdx.x;
    int v = (i < n) ? c[i] : 0;
    s[threadIdx.x] = v;
    __syncthreads();
    for (int d = 1; d < 1024; d <<= 1) {
        int t = (threadIdx.x >= d) ? s[threadIdx.x - d] : 0;
        __syncthreads();
        s[threadIdx.x] += t;
        __syncthreads();
    }
    int incl = s[threadIdx.x];
    if (i < n) of[i] = incl - v;
    if (threadIdx.x == 1023) bs[blk] = incl;
}

__global__ void k_scanC2(int* __restrict__ offs2, const int* __restrict__ bsum2,
                         int n, int nScan, int total) {
    __shared__ int s[64];
    int half = blockIdx.x / nScan;
    int blk  = blockIdx.x % nScan;
    int* of = offs2 + (size_t)half * (n + 1);
    const int* bs = bsum2 + half * 64;
    if (threadIdx.x < 64) s[threadIdx.x] = (threadIdx.x < nScan) ? bs[threadIdx.x] : 0;
    __syncthreads();
    if (threadIdx.x < 64) {
        for (int d = 1; d < 64; d <<= 1) {
            int t = (threadIdx.x >= d) ? s[threadIdx.x - d] : 0;
            __syncthreads();
            s[threadIdx.x] += t;
            __syncthreads();
        }
    } else {
        for (int d = 1; d < 64; d <<= 1) { __syncthreads(); __syncthreads(); }
    }
    int base = (blk == 0) ? 0 : s[blk - 1];
    int i = blk * 1024 + threadIdx.x;
    if (i < n) of[i] += base;
    else if (i == n) of[n] = total;
}

// ---------------- fused place + edge-MLP + permInv (hE bf16) ----------------

__global__ void k_place_he(const int* __restrict__ src, const int* __restrict__ dst,
                           const int* __restrict__ rankS, const int* __restrict__ rankD,
                           const int* __restrict__ offsS, const int* __restrict__ offsD,
                           const float* __restrict__ ea, const float* __restrict__ w1,
                           const float* __restrict__ b1,
                           u16* __restrict__ hE, int* __restrict__ permInv, int E_) {
    __shared__ float w1s[EFD * D];
    __shared__ float b1s[D];
    if (threadIdx.x < EFD * D) w1s[threadIdx.x] = w1[threadIdx.x];
    if (threadIdx.x < D) b1s[threadIdx.x] = b1[threadIdx.x];
    __syncthreads();
    int e = blockIdx.x * 256 + threadIdx.x;
    if (e >= E_) return;
    int p = offsS[src[e]] + rankS[e];
    int q = offsD[dst[e]] + rankD[e];
    permInv[p] = q;
    const float4* a4 = (const float4*)(ea + (size_t)e * EFD);
    float4 x0 = a4[0], x1 = a4[1];
    u32 pk[8];
#pragma unroll
    for (int v = 0; v < 8; v++) {
        float o0, o1;
#pragma unroll
        for (int h = 0; h < 2; h++) {
            int o = 2 * v + h;
            float u0 = x0.x * w1s[0 * D + o] + x0.y * w1s[1 * D + o]
                     + x0.z * w1s[2 * D + o] + x0.w * w1s[3 * D + o];
            float u1 = x1.x * w1s[4 * D + o] + x1.y * w1s[5 * D + o]
                     + x1.z * w1s[6 * D + o] + x1.w * w1s[7 * D + o];
            float t = tanhf(b1s[o] + u0 + u1);
            if (h == 0) o0 = t; else o1 = t;
        }
        pk[v] = (u32)f2bf(o0) | ((u32)f2bf(o1) << 16);
    }
    uint4* h8 = (uint4*)(hE + (size_t)p * D);
    h8[0] = make_uint4(pk[0], pk[1], pk[2], pk[3]);
    h8[1] = make_uint4(pk[4], pk[5], pk[6], pk[7]);
}

// ---------------- per-layer FUSED: BN + MFMA T-tile + messages (LDS-staged bulk hE) ----------------
// T(16x272) = h(16x16)·W2eff(16x272) via mfma_f32_16x16x32_bf16, K padded 16->32 (zero quads).
// W2eff staged once per block as bf16 B-fragments in LDS. Wave w handles tiles t = w, w+4, ...
// Message phase identical to r12 (chunked hE double-buffer, permInv shfl broadcast).

#define SBSTRIDE 17   // uint4 stride per group buffer (bank-conflict padding)

__global__ void k_Tmsg(const float* __restrict__ hin, const float* __restrict__ statsPrev,
                       const float* __restrict__ gamma, const float* __restrict__ beta,
                       float* __restrict__ hout, const float* __restrict__ w2,
                       const float* __restrict__ b2, const u16* __restrict__ hE,
                       const int* __restrict__ offsS, const int* __restrict__ permInv,
                       u16* __restrict__ msg, int n, int useBN) {
    __shared__ float hs[16 * D];
    __shared__ float Tt[16 * TSTRIDE];
    __shared__ float sstats[32];
    __shared__ u16 Bls[17 * 32 * 8];      // B frags, lanes 0..31 (k<16); quads 2,3 are zero
    __shared__ uint4 sbuf[4 * 2 * 4 * SBSTRIDE + 4];   // [wave][buf][group][17]
    int tid = threadIdx.x;
    int j = tid >> 4, o = tid & 15;
    int w = tid >> 6, jj = j & 3;
    int lane = tid & 63;
    int base = blockIdx.x * 16;
    int node = base + j;
    float fn = (float)n;
    int p0 = 0, p1 = 0;
    if (node < n) { p0 = offsS[node]; p1 = offsS[node + 1]; }
    int deg = p1 - p0;
    int nCh = (deg + 7) >> 3;
    uint4* buf0 = &sbuf[((w * 2 + 0) * 4 + jj) * SBSTRIDE];
    uint4* buf1 = &sbuf[((w * 2 + 1) * 4 + jj) * SBSTRIDE];

    // chunk-0 prefetch (global latency hides under staging + T phase)
    uint4 regH = make_uint4(0, 0, 0, 0);
    int regQ = 0;
    if (deg > 0) {
        int pr = p0 + (o >> 1);
        int pc = (pr < p1) ? pr : p1 - 1;
        regH = ((const uint4*)(hE + (size_t)pc * D))[o & 1];
        if (o < 8) {
            int pq = p0 + o;
            regQ = permInv[(pq < p1) ? pq : p1 - 1];
        }
    }

    // stage B fragments (once per block): entry e=(t,l,jb): k=(l>>4)*8+jb, c=16t+(l&15)
    for (int e = tid; e < 17 * 256; e += 256) {
        int t = e >> 8, rem = e & 255;
        int l = rem >> 3, jb = rem & 7;
        int k = ((l >> 4) << 3) + jb;
        int c = (t << 4) + (l & 15);
        float v = (c < 256) ? w2[((c >> 4) << 8) + (k << 4) + (c & 15)]
                            : b2[(k << 4) + (c - 256)];
        Bls[e] = f2bf(v);
    }
    if (useBN && tid < 32) {
        float a = 0.f;
#pragma unroll 8
        for (int r = 0; r < NREP; r++) a += statsPrev[r * 32 + tid];
        sstats[tid] = a;
    }
    __syncthreads();
    {   // stage h rows (apply BN+tanh of previous layer if needed)
        float hv = 0.f;
        if (node < n) {
            float xin = hin[(size_t)node * D + o];
            if (useBN) {
                float mu = sstats[o] / fn;
                float var = sstats[16 + o] / fn - mu * mu;
                hv = tanhf((xin - mu) * rsqrtf(var + 1e-5f) * gamma[o] + beta[o]);
                hout[(size_t)node * D + o] = hv;
            } else {
                hv = xin;
            }
        }
        hs[tid] = hv;   // hs[node_in_tile*16 + feat]
    }
    __syncthreads();
    {   // T-tile via MFMA: wave w does tiles t = w, w+4, w+8, ...
        int quad = lane >> 4;
        int m = lane & 15;                 // A row (node) / B,C col
        short8 afr = {0, 0, 0, 0, 0, 0, 0, 0};
        if (quad < 2) {                    // k = quad*8 + i, zero-padded K 16->32
            const float* hp = &hs[m * 16 + quad * 8];
#pragma unroll
            for (int i = 0; i < 8; i++) afr[i] = (short)f2bf(hp[i]);
        }
        for (int t = w; t < 17; t += 4) {
            short8 bfr = {0, 0, 0, 0, 0, 0, 0, 0};
            if (quad < 2) bfr = *(const short8*)&Bls[(t * 32 + lane) * 8];
            f32x4 cfr = {0.f, 0.f, 0.f, 0.f};
            cfr = __builtin_amdgcn_mfma_f32_16x16x32_bf16(afr, bfr, cfr, 0, 0, 0);
            int cbase = t * 16 + m;        // C: col = lane&15, row = quad*4 + r
#pragma unroll
            for (int r = 0; r < 4; r++)
                Tt[(quad * 4 + r) * TSTRIDE + cbase] = cfr[r];
        }
    }
    __syncthreads();
    if (node < n && deg > 0) {   // message phase: chunked LDS-staged degree loop
        float tr[16];
#pragma unroll
        for (int j2 = 0; j2 < 16; j2++) tr[j2] = Tt[j * TSTRIDE + j2 * 16 + o];
        float tb = Tt[j * TSTRIDE + 256 + o];
        buf0[o] = regH;                      // stage chunk 0
        for (int c = 0; c < nCh; c++) {
            uint4* cur = (c & 1) ? buf1 : buf0;
            uint4* nxt = (c & 1) ? buf0 : buf1;
            uint4 nH; int nQ = 0;
            if (c + 1 < nCh) {               // issue next chunk's global loads now
                int pr = p0 + (c + 1) * 8 + (o >> 1);
                int pc = (pr < p1) ? pr : p1 - 1;
                nH = ((const uint4*)(hE + (size_t)pc * D))[o & 1];
                if (o < 8) {
                    int pq = p0 + (c + 1) * 8 + o;
                    nQ = permInv[(pq < p1) ? pq : p1 - 1];
                }
            }
            int eMax = deg - c * 8;
            if (eMax > 8) eMax = 8;
            for (int i = 0; i < eMax; i++) {
                uint4 r0 = cur[2 * i], r1 = cur[2 * i + 1];   // broadcast reads
                int qe = __shfl(regQ, jj * 16 + i);
                float e[16];
                unpack8(r0, e); unpack8(r1, e + 8);
                float s0 = e[0]  * tr[0]  + e[1]  * tr[1]  + e[2]  * tr[2]  + e[3]  * tr[3];
                float s1 = e[4]  * tr[4]  + e[5]  * tr[5]  + e[6]  * tr[6]  + e[7]  * tr[7];
                float s2 = e[8]  * tr[8]  + e[9]  * tr[9]  + e[10] * tr[10] + e[11] * tr[11];
                float s3 = e[12] * tr[12] + e[13] * tr[13] + e[14] * tr[14] + e[15] * tr[15];
                msg[(size_t)qe * D + o] = f2bf(tb + ((s0 + s1) + (s2 + s3)));
            }
            if (c + 1 < nCh) {
                nxt[o] = nH;                 // stage next chunk
                regQ = nQ;
            }
        }
    }
}

// ---------------- per-layer: dst aggregation (sequential bf16 msg read) + root + BN stats ----------------

__global__ void k_agg(const float* __restrict__ h, const u16* __restrict__ msg,
                      const int* __restrict__ offsD, const float* __restrict__ root_l,
                      const float* __restrict__ cbias, float* __restrict__ hpre,
                      float* __restrict__ statsR, int n) {
    __shared__ float rootS[D * D];
    __shared__ float red[256], red2[256];
    if (threadIdx.x < D * D) rootS[threadIdx.x] = root_l[threadIdx.x];
    __syncthreads();
    int slot = threadIdx.x >> 4, o = threadIdx.x & 15;
    int node = blockIdx.x * 16 + slot;
    float acc = 0.f;
    if (node < n) {
        int p0 = offsD[node], p1 = offsD[node + 1];
        float sum = 0.f;
        int p = p0;
        for (; p + 8 <= p1; p += 8) {
            float a0 = __uint_as_float((u32)msg[(size_t)(p + 0) * D + o] << 16);
            float a1 = __uint_as_float((u32)msg[(size_t)(p + 1) * D + o] << 16);
            float a2 = __uint_as_float((u32)msg[(size_t)(p + 2) * D + o] << 16);
            float a3 = __uint_as_float((u32)msg[(size_t)(p + 3) * D + o] << 16);
            float a4 = __uint_as_float((u32)msg[(size_t)(p + 4) * D + o] << 16);
            float a5 = __uint_as_float((u32)msg[(size_t)(p + 5) * D + o] << 16);
            float a6 = __uint_as_float((u32)msg[(size_t)(p + 6) * D + o] << 16);
            float a7 = __uint_as_float((u32)msg[(size_t)(p + 7) * D + o] << 16);
            sum += ((a0 + a1) + (a2 + a3)) + ((a4 + a5) + (a6 + a7));
        }
        for (; p < p1; p++) sum += __uint_as_float((u32)msg[(size_t)p * D + o] << 16);
        float deg = (float)((p1 - p0) > 1 ? (p1 - p0) : 1);
        const float* hr = h + (size_t)node * D;
        float r0 = hr[0]  * rootS[0 * D + o]  + hr[1]  * rootS[1 * D + o]
                 + hr[2]  * rootS[2 * D + o]  + hr[3]  * rootS[3 * D + o];
        float r1 = hr[4]  * rootS[4 * D + o]  + hr[5]  * rootS[5 * D + o]
                 + hr[6]  * rootS[6 * D + o]  + hr[7]  * rootS[7 * D + o];
        float r2 = hr[8]  * rootS[8 * D + o]  + hr[9]  * rootS[9 * D + o]
                 + hr[10] * rootS[10 * D + o] + hr[11] * rootS[11 * D + o];
        float r3 = hr[12] * rootS[12 * D + o] + hr[13] * rootS[13 * D + o]
                 + hr[14] * rootS[14 * D + o] + hr[15] * rootS[15 * D + o];
        acc = sum / deg + cbias[o] + ((r0 + r1) + (r2 + r3));
        hpre[(size_t)node * D + o] = acc;
    }
    red[threadIdx.x] = acc;
    red2[threadIdx.x] = acc * acc;
    __syncthreads();
    for (int off = 128; off >= 16; off >>= 1) {
        if (threadIdx.x < off) {
            red[threadIdx.x] += red[threadIdx.x + off];
            red2[threadIdx.x] += red2[threadIdx.x + off];
        }
        __syncthreads();
    }
    if (threadIdx.x < 32) {
        float v = (threadIdx.x < 16) ? red[threadIdx.x] : red2[threadIdx.x - 16];
        atomicAdd(&statsR[(blockIdx.x & (NREP - 1)) * 32 + threadIdx.x], v);
    }
}

// ---------------- fused readout ----------------

__global__ void k_readout(const float* __restrict__ hpre, const float* __restrict__ statsR,
                          const float* __restrict__ gamma, const float* __restrict__ beta,
                          const int* __restrict__ lengths,
                          const float* __restrict__ w1, const float* __restrict__ b1,
                          const float* __restrict__ w2, const float* __restrict__ b2,
                          float* __restrict__ outHidden, float* __restrict__ outPooled,
                          float* __restrict__ fcOut, float* __restrict__ lsmOut,
                          int Gc, int n) {
    __shared__ int sl[512];
    __shared__ float sstats[32];
    int tid = threadIdx.x;
    int g = blockIdx.x;
    if (tid < 32) {
        float a = 0.f;
#pragma unroll 8
        for (int r = 0; r < NREP; r++) a += statsR[r * 32 + tid];
        sstats[tid] = a;
    }
    int v = (tid < Gc) ? lengths[tid] : 0;
    sl[tid] = v;
    __syncthreads();
    for (int d = 1; d < 512; d <<= 1) {
        int t = (tid >= d) ? sl[tid - d] : 0;
        __syncthreads();
        sl[tid] += t;
        __syncthreads();
    }
    int n1 = sl[g];
    int n0 = n1 - lengths[g];
    float fn = (float)n;
    int slot = tid >> 4, o = tid & 15;
    float mu = sstats[o] / fn;
    float var = sstats[16 + o] / fn - mu * mu;
    float rstd = rsqrtf(var + 1e-5f);
    float gm = gamma[o], bt = beta[o];
    float s = 0.f, mx = -3.402823466e38f, mn = 3.402823466e38f;
    for (int nd = n0 + slot; nd < n1; nd += 32) {
        float xin = hpre[(size_t)nd * D + o];
        float x = tanhf((xin - mu) * rstd * gm + bt);
        outHidden[(size_t)nd * D + o] = x;
        s += x;
        mx = fmaxf(mx, x);
        mn = fminf(mn, x);
    }
    __shared__ float rs[512], rmx[512], rmn[512];
    rs[tid] = s; rmx[tid] = mx; rmn[tid] = mn;
    __syncthreads();
    for (int off = 256; off >= 16; off >>= 1) {
        if (tid < off) {
            rs[tid] += rs[tid + off];
            rmx[tid] = fmaxf(rmx[tid], rmx[tid + off]);
            rmn[tid] = fminf(rmn[tid], rmn[tid + off]);
        }
        __syncthreads();
    }
    __shared__ float p64[64], t16[16], f10[10];
    __shared__ float mred, lred;
    if (tid < 16) {
        float cnt = fmaxf((float)(n1 - n0), 1.f);
        float sum = rs[tid];
        float* row = outPooled + (size_t)g * 64;
        float mean = sum / cnt;
        p64[tid] = mean;          row[tid] = mean;
        p64[16 + tid] = rmx[tid]; row[16 + tid] = rmx[tid];
        p64[32 + tid] = rmn[tid]; row[32 + tid] = rmn[tid];
        p64[48 + tid] = sum;      row[48 + tid] = sum;
    }
    __syncthreads();
    if (tid < 16) {
        float a = b1[tid];
        for (int k = 0; k < 64; k++) a += p64[k] * w1[k * 16 + tid];
        t16[tid] = tanhf(a);
    }
    __syncthreads();
    if (tid < 10) {
        float a = b2[tid];
        for (int oo = 0; oo < 16; oo++) a += t16[oo] * w2[oo * 10 + tid];
        f10[tid] = a;
        fcOut[(size_t)g * 10 + tid] = a;
    }
    __syncthreads();
    if (tid == 0) {
        float m = f10[0];
        for (int c = 1; c < 10; c++) m = fmaxf(m, f10[c]);
        float se = 0.f;
        for (int c = 0; c < 10; c++) se += expf(f10[c] - m);
        mred = m;
        lred = logf(se);
    }
    __syncthreads();
    if (tid < 10)
        lsmOut[(size_t)g * 10 + tid] = f10[tid] - mred - lred;
}

// ---------------- host ----------------

extern "C" void kernel_launch(void* const* d_in, const int* in_sizes, int n_in,
                              void* d_out, int out_size, void* d_ws, size_t ws_size,
                              hipStream_t stream) {
    const float* x    = (const float*)d_in[0];
    const float* ea   = (const float*)d_in[1];
    const float* ew1  = (const float*)d_in[2];
    const float* eb1  = (const float*)d_in[3];
    const float* ew2  = (const float*)d_in[4];
    const float* eb2  = (const float*)d_in[5];
    const float* root = (const float*)d_in[6];
    const float* cb   = (const float*)d_in[7];
    const float* gam  = (const float*)d_in[8];
    const float* bet  = (const float*)d_in[9];
    const float* f1w  = (const float*)d_in[10];
    const float* f1b  = (const float*)d_in[11];
    const float* f2w  = (const float*)d_in[12];
    const float* f2b  = (const float*)d_in[13];
    const int* eidx   = (const int*)d_in[14];
    const int* lens   = (const int*)d_in[15];

    int N  = in_sizes[0] / D;
    int E_ = in_sizes[1] / EFD;
    int Gc = in_sizes[15];
    const int* srcIdx = eidx;
    const int* dstIdx = eidx + E_;

    float* outHidden = (float*)d_out;
    float* outPooled = outHidden + (size_t)N * D;
    float* outFc     = outPooled + (size_t)Gc * 4 * D;
    float* outLsm    = outFc + (size_t)Gc * 10;

    char* wsp = (char*)d_ws;
    size_t off = 0;
    auto alloc = [&](size_t bytes) -> void* {
        void* p = wsp + off;
        off = (off + bytes + 255) & ~(size_t)255;
        return p;
    };
    int*   cnt2    = (int*)alloc((size_t)2 * N * 4);
    int*   offs2   = (int*)alloc((size_t)2 * (N + 1) * 4);
    int*   bsum2   = (int*)alloc(128 * 4);
    int*   rankS   = (int*)alloc((size_t)E_ * 4);
    int*   rankD   = (int*)alloc((size_t)E_ * 4);
    int*   permInv = (int*)alloc((size_t)E_ * 4);
    u16*   hE      = (u16*)alloc((size_t)E_ * D * 2);
    u16*   msg     = (u16*)alloc((size_t)E_ * D * 2);
    float* bufA    = (float*)alloc((size_t)N * D * 4);
    float* tmp     = (float*)alloc((size_t)N * D * 4);
    float* statsR3 = (float*)alloc((size_t)3 * NREP * 32 * 4);

    int* offsS = offs2;
    int* offsD = offs2 + (N + 1);
    int nScan = (N + 1023) / 1024;

    k_zero2<<<(2 * N + 255) / 256, 256, 0, stream>>>(cnt2, 2 * N, statsR3, 3 * NREP * 32);
    k_rank2<<<(E_ + 255) / 256, 256, 0, stream>>>(srcIdx, dstIdx, cnt2, cnt2 + N,
                                                  rankS, rankD, E_);
    k_scanA2<<<2 * nScan, 1024, 0, stream>>>(cnt2, offs2, bsum2, N, nScan);
    k_scanC2<<<2 * nScan, 1024, 0, stream>>>(offs2, bsum2, N, nScan, E_);
    k_place_he<<<(E_ + 255) / 256, 256, 0, stream>>>(srcIdx, dstIdx, rankS, rankD,
                                                     offsS, offsD, ea, ew1, eb1,
                                                     hE, permInv, E_);

    for (int l = 0; l < 3; l++) {
        const float* hin   = (l == 0) ? x : tmp;
        const float* hroot = (l == 0) ? x : bufA;
        float* statsCur = statsR3 + (size_t)l * NREP * 32;
        const float* statsPrev = statsR3 + (size_t)(l - 1) * NREP * 32;
        k_Tmsg<<<(N + 15) / 16, 256, 0, stream>>>(
            hin, (l == 0) ? nullptr : statsPrev,
            (l == 0) ? nullptr : gam + (size_t)(l - 1) * 16,
            (l == 0) ? nullptr : bet + (size_t)(l - 1) * 16,
            bufA, ew2, eb2, hE, offsS, permInv, msg, N, (l == 0) ? 0 : 1);
        k_agg<<<(N + 15) / 16, 256, 0, stream>>>(hroot, msg, offsD,
                                                 root + (size_t)l * 256, cb + (size_t)l * 16,
                                                 tmp, statsCur, N);
    }

    k_readout<<<Gc, 512, 0, stream>>>(tmp, statsR3 + (size_t)2 * NREP * 32,
                                      gam + 32, bet + 32, lens, f1w, f1b, f2w, f2b,
                                      outHidden, outPooled, outFc, outLsm, Gc, N);
}

// Round 14
// 300.972 us; speedup vs baseline: 1.0555x; 1.0555x over previous
//
#include <hip/hip_runtime.h>

#define D 16
#define EFD 8
#define NREP 64       // BN-stats replica buffers (breaks atomic same-line contention)
#define TSTRIDE 276   // Tt node stride: 4*276%32==16 -> quad rows on disjoint half-banks (<=2-way, free)

typedef unsigned short u16;
typedef unsigned int u32;
typedef __attribute__((ext_vector_type(8))) short short8;  // 8 bf16 = 4 VGPRs (MFMA A/B frag)
typedef __attribute__((ext_vector_type(4))) float f32x4;   // MFMA C/D frag

__device__ __forceinline__ u16 f2bf(float x) {          // round-to-nearest-even
    u32 u = __float_as_uint(x);
    u += 0x7fffu + ((u >> 16) & 1u);
    return (u16)(u >> 16);
}
__device__ __forceinline__ void unpack8(uint4 u, float* f) {
    f[0] = __uint_as_float(u.x << 16); f[1] = __uint_as_float(u.x & 0xffff0000u);
    f[2] = __uint_as_float(u.y << 16); f[3] = __uint_as_float(u.y & 0xffff0000u);
    f[4] = __uint_as_float(u.z << 16); f[5] = __uint_as_float(u.z & 0xffff0000u);
    f[6] = __uint_as_float(u.w << 16); f[7] = __uint_as_float(u.w & 0xffff0000u);
}

// ---------------- zero scratch ----------------

__global__ void k_zero2(int* a, int na, float* b, int nb) {
    int i = blockIdx.x * 256 + threadIdx.x;
    if (i < na) a[i] = 0;
    if (i < nb) b[i] = 0.f;
}

// ---------------- rank: one atomic per edge per side ----------------

__global__ void k_rank2(const int* __restrict__ src, const int* __restrict__ dst,
                        int* __restrict__ cntS, int* __restrict__ cntD,
                        int* __restrict__ rankS, int* __restrict__ rankD, int E_) {
    int e = blockIdx.x * 256 + threadIdx.x;
    if (e < E_) {
        rankS[e] = atomicAdd(&cntS[src[e]], 1);
        rankD[e] = atomicAdd(&cntD[dst[e]], 1);
    }
}

// ---------------- scans over cntS|cntD ----------------

__global__ void k_scanA2(const int* __restrict__ cnt2, int* __restrict__ offs2,
                         int* __restrict__ bsum2, int n, int nScan) {
    __shared__ int s[1024];
    int half = blockIdx.x / nScan;
    int blk  = blockIdx.x % nScan;
    const int* c = cnt2 + (size_t)half * n;
    int* of = offs2 + (size_t)half * (n + 1);
    int* bs = bsum2 + half * 64;
    int i = blk * 1024 + threadIdx.x;
    int v = (i < n) ? c[i] : 0;
    s[threadIdx.x] = v;
    __syncthreads();
    for (int d = 1; d < 1024; d <<= 1) {
        int t = (threadIdx.x >= d) ? s[threadIdx.x - d] : 0;
        __syncthreads();
        s[threadIdx.x] += t;
        __syncthreads();
    }
    int incl = s[threadIdx.x];
    if (i < n) of[i] = incl - v;
    if (threadIdx.x == 1023) bs[blk] = incl;
}

__global__ void k_scanC2(int* __restrict__ offs2, const int* __restrict__ bsum2,
                         int n, int nScan, int total) {
    __shared__ int s[64];
    int half = blockIdx.x / nScan;
    int blk  = blockIdx.x % nScan;
    int* of = offs2 + (size_t)half * (n + 1);
    const int* bs = bsum2 + half * 64;
    if (threadIdx.x < 64) s[threadIdx.x] = (threadIdx.x < nScan) ? bs[threadIdx.x] : 0;
    __syncthreads();
    if (threadIdx.x < 64) {
        for (int d = 1; d < 64; d <<= 1) {
            int t = (threadIdx.x >= d) ? s[threadIdx.x - d] : 0;
            __syncthreads();
            s[threadIdx.x] += t;
            __syncthreads();
        }
    } else {
        for (int d = 1; d < 64; d <<= 1) { __syncthreads(); __syncthreads(); }
    }
    int base = (blk == 0) ? 0 : s[blk - 1];
    int i = blk * 1024 + threadIdx.x;
    if (i < n) of[i] += base;
    else if (i == n) of[n] = total;
}

// ---------------- fused place + edge-MLP + permInv (hE bf16) ----------------

__global__ void k_place_he(const int* __restrict__ src, const int* __restrict__ dst,
                           const int* __restrict__ rankS, const int* __restrict__ rankD,
                           const int* __restrict__ offsS, const int* __restrict__ offsD,
                           const float* __restrict__ ea, const float* __restrict__ w1,
                           const float* __restrict__ b1,
                           u16* __restrict__ hE, int* __restrict__ permInv, int E_) {
    __shared__ float w1s[EFD * D];
    __shared__ float b1s[D];
    if (threadIdx.x < EFD * D) w1s[threadIdx.x] = w1[threadIdx.x];
    if (threadIdx.x < D) b1s[threadIdx.x] = b1[threadIdx.x];
    __syncthreads();
    int e = blockIdx.x * 256 + threadIdx.x;
    if (e >= E_) return;
    int p = offsS[src[e]] + rankS[e];
    int q = offsD[dst[e]] + rankD[e];
    permInv[p] = q;
    const float4* a4 = (const float4*)(ea + (size_t)e * EFD);
    float4 x0 = a4[0], x1 = a4[1];
    u32 pk[8];
#pragma unroll
    for (int v = 0; v < 8; v++) {
        float o0, o1;
#pragma unroll
        for (int h = 0; h < 2; h++) {
            int o = 2 * v + h;
            float u0 = x0.x * w1s[0 * D + o] + x0.y * w1s[1 * D + o]
                     + x0.z * w1s[2 * D + o] + x0.w * w1s[3 * D + o];
            float u1 = x1.x * w1s[4 * D + o] + x1.y * w1s[5 * D + o]
                     + x1.z * w1s[6 * D + o] + x1.w * w1s[7 * D + o];
            float t = tanhf(b1s[o] + u0 + u1);
            if (h == 0) o0 = t; else o1 = t;
        }
        pk[v] = (u32)f2bf(o0) | ((u32)f2bf(o1) << 16);
    }
    uint4* h8 = (uint4*)(hE + (size_t)p * D);
    h8[0] = make_uint4(pk[0], pk[1], pk[2], pk[3]);
    h8[1] = make_uint4(pk[4], pk[5], pk[6], pk[7]);
}

// ---------------- per-layer FUSED: BN + MFMA T-tile + messages ----------------
// T(16x272) = h(16x16)·W2eff(16x272) via mfma_f32_16x16x32_bf16, K padded 16->32 (zero quads).
// B fragments built from L1-resident w2 loads per tile (no LDS staging). Layout verified r13.
// Message phase: r11-style 1-deep pipelined degree loop (no sbuf). LDS ~18.8 KB/block.

__global__ void k_Tmsg(const float* __restrict__ hin, const float* __restrict__ statsPrev,
                       const float* __restrict__ gamma, const float* __restrict__ beta,
                       float* __restrict__ hout, const float* __restrict__ w2,
                       const float* __restrict__ b2, const u16* __restrict__ hE,
                       const int* __restrict__ offsS, const int* __restrict__ permInv,
                       u16* __restrict__ msg, int n, int useBN) {
    __shared__ float hs[16 * D];
    __shared__ float Tt[16 * TSTRIDE];    // [node][col 0..255 | 256..271 bias]
    __shared__ float sstats[32];
    int tid = threadIdx.x;
    int j = tid >> 4, o = tid & 15;
    int w = tid >> 6;
    int lane = tid & 63;
    int base = blockIdx.x * 16;
    int node = base + j;
    float fn = (float)n;
    int p0 = 0, p1 = 0;
    if (node < n) { p0 = offsS[node]; p1 = offsS[node + 1]; }
    // first-edge prefetch (global latency hides under the T phase)
    int qPre = 0;
    uint4 a0, a1;
    if (p0 < p1) {
        qPre = permInv[p0];
        const uint4* he8 = (const uint4*)(hE + (size_t)p0 * D);
        a0 = he8[0]; a1 = he8[1];
    }
    if (useBN && tid < 32) {
        float a = 0.f;
#pragma unroll 8
        for (int r = 0; r < NREP; r++) a += statsPrev[r * 32 + tid];
        sstats[tid] = a;
    }
    __syncthreads();
    {   // stage h rows (apply BN+tanh of previous layer if needed)
        float hv = 0.f;
        if (node < n) {
            float xin = hin[(size_t)node * D + o];
            if (useBN) {
                float mu = sstats[o] / fn;
                float var = sstats[16 + o] / fn - mu * mu;
                hv = tanhf((xin - mu) * rsqrtf(var + 1e-5f) * gamma[o] + beta[o]);
                hout[(size_t)node * D + o] = hv;
            } else {
                hv = xin;
            }
        }
        hs[tid] = hv;   // hs[node_in_tile*16 + feat]
    }
    __syncthreads();
    {   // T-tile via MFMA: wave w does column-tiles t = w, w+4, w+8, ...
        int quad = lane >> 4;
        int m = lane & 15;                 // A row (node) / B,C col
        short8 afr = {0, 0, 0, 0, 0, 0, 0, 0};
        if (quad < 2) {                    // A[m][k=quad*8+i], zero-padded K 16->32
            const float* hp = &hs[m * 16 + quad * 8];
#pragma unroll
            for (int i = 0; i < 8; i++) afr[i] = (short)f2bf(hp[i]);
        }
        for (int t = w; t < 17; t += 4) {
            short8 bfr = {0, 0, 0, 0, 0, 0, 0, 0};
            if (quad < 2) {                // B[k=quad*8+jb][n=m]; col c = t*16+m
#pragma unroll
                for (int jb = 0; jb < 8; jb++) {
                    int k = (quad << 3) + jb;
                    float v = (t < 16) ? w2[(t << 8) + (k << 4) + m]
                                       : b2[(k << 4) + m];
                    bfr[jb] = (short)f2bf(v);
                }
            }
            f32x4 cfr = {0.f, 0.f, 0.f, 0.f};
            cfr = __builtin_amdgcn_mfma_f32_16x16x32_bf16(afr, bfr, cfr, 0, 0, 0);
            int cbase = t * 16 + m;        // C: col = lane&15, row = quad*4 + r
#pragma unroll
            for (int r = 0; r < 4; r++)
                Tt[(quad * 4 + r) * TSTRIDE + cbase] = cfr[r];
        }
    }
    __syncthreads();
    if (node < n) {   // messages: thread (j,o); T row in registers; 1-deep pipelined loop
        float tr[16];
#pragma unroll
        for (int j2 = 0; j2 < 16; j2++) tr[j2] = Tt[j * TSTRIDE + j2 * 16 + o];
        float tb = Tt[j * TSTRIDE + 256 + o];
        int q = qPre;
        for (int p = p0; p < p1; p++) {
            uint4 c0 = a0, c1 = a1;
            int qc = q;
            if (p + 1 < p1) {               // prefetch next edge before consuming current
                q = permInv[p + 1];
                const uint4* n8 = (const uint4*)(hE + (size_t)(p + 1) * D);
                a0 = n8[0]; a1 = n8[1];
            }
            float e[16];
            unpack8(c0, e); unpack8(c1, e + 8);
            float s0 = e[0]  * tr[0]  + e[1]  * tr[1]  + e[2]  * tr[2]  + e[3]  * tr[3];
            float s1 = e[4]  * tr[4]  + e[5]  * tr[5]  + e[6]  * tr[6]  + e[7]  * tr[7];
            float s2 = e[8]  * tr[8]  + e[9]  * tr[9]  + e[10] * tr[10] + e[11] * tr[11];
            float s3 = e[12] * tr[12] + e[13] * tr[13] + e[14] * tr[14] + e[15] * tr[15];
            msg[(size_t)qc * D + o] = f2bf(tb + ((s0 + s1) + (s2 + s3)));
        }
    }
}

// ---------------- per-layer: dst aggregation (sequential bf16 msg read) + root + BN stats ----------------

__global__ void k_agg(const float* __restrict__ h, const u16* __restrict__ msg,
                      const int* __restrict__ offsD, const float* __restrict__ root_l,
                      const float* __restrict__ cbias, float* __restrict__ hpre,
                      float* __restrict__ statsR, int n) {
    __shared__ float rootS[D * D];
    __shared__ float red[256], red2[256];
    if (threadIdx.x < D * D) rootS[threadIdx.x] = root_l[threadIdx.x];
    __syncthreads();
    int slot = threadIdx.x >> 4, o = threadIdx.x & 15;
    int node = blockIdx.x * 16 + slot;
    float acc = 0.f;
    if (node < n) {
        int p0 = offsD[node], p1 = offsD[node + 1];
        float sum = 0.f;
        int p = p0;
        for (; p + 8 <= p1; p += 8) {
            float a0 = __uint_as_float((u32)msg[(size_t)(p + 0) * D + o] << 16);
            float a1 = __uint_as_float((u32)msg[(size_t)(p + 1) * D + o] << 16);
            float a2 = __uint_as_float((u32)msg[(size_t)(p + 2) * D + o] << 16);
            float a3 = __uint_as_float((u32)msg[(size_t)(p + 3) * D + o] << 16);
            float a4 = __uint_as_float((u32)msg[(size_t)(p + 4) * D + o] << 16);
            float a5 = __uint_as_float((u32)msg[(size_t)(p + 5) * D + o] << 16);
            float a6 = __uint_as_float((u32)msg[(size_t)(p + 6) * D + o] << 16);
            float a7 = __uint_as_float((u32)msg[(size_t)(p + 7) * D + o] << 16);
            sum += ((a0 + a1) + (a2 + a3)) + ((a4 + a5) + (a6 + a7));
        }
        for (; p < p1; p++) sum += __uint_as_float((u32)msg[(size_t)p * D + o] << 16);
        float deg = (float)((p1 - p0) > 1 ? (p1 - p0) : 1);
        const float* hr = h + (size_t)node * D;
        float r0 = hr[0]  * rootS[0 * D + o]  + hr[1]  * rootS[1 * D + o]
                 + hr[2]  * rootS[2 * D + o]  + hr[3]  * rootS[3 * D + o];
        float r1 = hr[4]  * rootS[4 * D + o]  + hr[5]  * rootS[5 * D + o]
                 + hr[6]  * rootS[6 * D + o]  + hr[7]  * rootS[7 * D + o];
        float r2 = hr[8]  * rootS[8 * D + o]  + hr[9]  * rootS[9 * D + o]
                 + hr[10] * rootS[10 * D + o] + hr[11] * rootS[11 * D + o];
        float r3 = hr[12] * rootS[12 * D + o] + hr[13] * rootS[13 * D + o]
                 + hr[14] * rootS[14 * D + o] + hr[15] * rootS[15 * D + o];
        acc = sum / deg + cbias[o] + ((r0 + r1) + (r2 + r3));
        hpre[(size_t)node * D + o] = acc;
    }
    red[threadIdx.x] = acc;
    red2[threadIdx.x] = acc * acc;
    __syncthreads();
    for (int off = 128; off >= 16; off >>= 1) {
        if (threadIdx.x < off) {
            red[threadIdx.x] += red[threadIdx.x + off];
            red2[threadIdx.x] += red2[threadIdx.x + off];
        }
        __syncthreads();
    }
    if (threadIdx.x < 32) {
        float v = (threadIdx.x < 16) ? red[threadIdx.x] : red2[threadIdx.x - 16];
        atomicAdd(&statsR[(blockIdx.x & (NREP - 1)) * 32 + threadIdx.x], v);
    }
}

// ---------------- fused readout ----------------

__global__ void k_readout(const float* __restrict__ hpre, const float* __restrict__ statsR,
                          const float* __restrict__ gamma, const float* __restrict__ beta,
                          const int* __restrict__ lengths,
                          const float* __restrict__ w1, const float* __restrict__ b1,
                          const float* __restrict__ w2, const float* __restrict__ b2,
                          float* __restrict__ outHidden, float* __restrict__ outPooled,
                          float* __restrict__ fcOut, float* __restrict__ lsmOut,
                          int Gc, int n) {
    __shared__ int sl[512];
    __shared__ float sstats[32];
    int tid = threadIdx.x;
    int g = blockIdx.x;
    if (tid < 32) {
        float a = 0.f;
#pragma unroll 8
        for (int r = 0; r < NREP; r++) a += statsR[r * 32 + tid];
        sstats[tid] = a;
    }
    int v = (tid < Gc) ? lengths[tid] : 0;
    sl[tid] = v;
    __syncthreads();
    for (int d = 1; d < 512; d <<= 1) {
        int t = (tid >= d) ? sl[tid - d] : 0;
        __syncthreads();
        sl[tid] += t;
        __syncthreads();
    }
    int n1 = sl[g];
    int n0 = n1 - lengths[g];
    float fn = (float)n;
    int slot = tid >> 4, o = tid & 15;
    float mu = sstats[o] / fn;
    float var = sstats[16 + o] / fn - mu * mu;
    float rstd = rsqrtf(var + 1e-5f);
    float gm = gamma[o], bt = beta[o];
    float s = 0.f, mx = -3.402823466e38f, mn = 3.402823466e38f;
    for (int nd = n0 + slot; nd < n1; nd += 32) {
        float xin = hpre[(size_t)nd * D + o];
        float x = tanhf((xin - mu) * rstd * gm + bt);
        outHidden[(size_t)nd * D + o] = x;
        s += x;
        mx = fmaxf(mx, x);
        mn = fminf(mn, x);
    }
    __shared__ float rs[512], rmx[512], rmn[512];
    rs[tid] = s; rmx[tid] = mx; rmn[tid] = mn;
    __syncthreads();
    for (int off = 256; off >= 16; off >>= 1) {
        if (tid < off) {
            rs[tid] += rs[tid + off];
            rmx[tid] = fmaxf(rmx[tid], rmx[tid + off]);
            rmn[tid] = fminf(rmn[tid], rmn[tid + off]);
        }
        __syncthreads();
    }
    __shared__ float p64[64], t16[16], f10[10];
    __shared__ float mred, lred;
    if (tid < 16) {
        float cnt = fmaxf((float)(n1 - n0), 1.f);
        float sum = rs[tid];
        float* row = outPooled + (size_t)g * 64;
        float mean = sum / cnt;
        p64[tid] = mean;          row[tid] = mean;
        p64[16 + tid] = rmx[tid]; row[16 + tid] = rmx[tid];
        p64[32 + tid] = rmn[tid]; row[32 + tid] = rmn[tid];
        p64[48 + tid] = sum;      row[48 + tid] = sum;
    }
    __syncthreads();
    if (tid < 16) {
        float a = b1[tid];
        for (int k = 0; k < 64; k++) a += p64[k] * w1[k * 16 + tid];
        t16[tid] = tanhf(a);
    }
    __syncthreads();
    if (tid < 10) {
        float a = b2[tid];
        for (int oo = 0; oo < 16; oo++) a += t16[oo] * w2[oo * 10 + tid];
        f10[tid] = a;
        fcOut[(size_t)g * 10 + tid] = a;
    }
    __syncthreads();
    if (tid == 0) {
        float m = f10[0];
        for (int c = 1; c < 10; c++) m = fmaxf(m, f10[c]);
        float se = 0.f;
        for (int c = 0; c < 10; c++) se += expf(f10[c] - m);
        mred = m;
        lred = logf(se);
    }
    __syncthreads();
    if (tid < 10)
        lsmOut[(size_t)g * 10 + tid] = f10[tid] - mred - lred;
}

// ---------------- host ----------------

extern "C" void kernel_launch(void* const* d_in, const int* in_sizes, int n_in,
                              void* d_out, int out_size, void* d_ws, size_t ws_size,
                              hipStream_t stream) {
    const float* x    = (const float*)d_in[0];
    const float* ea   = (const float*)d_in[1];
    const float* ew1  = (const float*)d_in[2];
    const float* eb1  = (const float*)d_in[3];
    const float* ew2  = (const float*)d_in[4];
    const float* eb2  = (const float*)d_in[5];
    const float* root = (const float*)d_in[6];
    const float* cb   = (const float*)d_in[7];
    const float* gam  = (const float*)d_in[8];
    const float* bet  = (const float*)d_in[9];
    const float* f1w  = (const float*)d_in[10];
    const float* f1b  = (const float*)d_in[11];
    const float* f2w  = (const float*)d_in[12];
    const float* f2b  = (const float*)d_in[13];
    const int* eidx   = (const int*)d_in[14];
    const int* lens   = (const int*)d_in[15];

    int N  = in_sizes[0] / D;
    int E_ = in_sizes[1] / EFD;
    int Gc = in_sizes[15];
    const int* srcIdx = eidx;
    const int* dstIdx = eidx + E_;

    float* outHidden = (float*)d_out;
    float* outPooled = outHidden + (size_t)N * D;
    float* outFc     = outPooled + (size_t)Gc * 4 * D;
    float* outLsm    = outFc + (size_t)Gc * 10;

    char* wsp = (char*)d_ws;
    size_t off = 0;
    auto alloc = [&](size_t bytes) -> void* {
        void* p = wsp + off;
        off = (off + bytes + 255) & ~(size_t)255;
        return p;
    };
    int*   cnt2    = (int*)alloc((size_t)2 * N * 4);
    int*   offs2   = (int*)alloc((size_t)2 * (N + 1) * 4);
    int*   bsum2   = (int*)alloc(128 * 4);
    int*   rankS   = (int*)alloc((size_t)E_ * 4);
    int*   rankD   = (int*)alloc((size_t)E_ * 4);
    int*   permInv = (int*)alloc((size_t)E_ * 4);
    u16*   hE      = (u16*)alloc((size_t)E_ * D * 2);
    u16*   msg     = (u16*)alloc((size_t)E_ * D * 2);
    float* bufA    = (float*)alloc((size_t)N * D * 4);
    float* tmp     = (float*)alloc((size_t)N * D * 4);
    float* statsR3 = (float*)alloc((size_t)3 * NREP * 32 * 4);

    int* offsS = offs2;
    int* offsD = offs2 + (N + 1);
    int nScan = (N + 1023) / 1024;

    k_zero2<<<(2 * N + 255) / 256, 256, 0, stream>>>(cnt2, 2 * N, statsR3, 3 * NREP * 32);
    k_rank2<<<(E_ + 255) / 256, 256, 0, stream>>>(srcIdx, dstIdx, cnt2, cnt2 + N,
                                                  rankS, rankD, E_);
    k_scanA2<<<2 * nScan, 1024, 0, stream>>>(cnt2, offs2, bsum2, N, nScan);
    k_scanC2<<<2 * nScan, 1024, 0, stream>>>(offs2, bsum2, N, nScan, E_);
    k_place_he<<<(E_ + 255) / 256, 256, 0, stream>>>(srcIdx, dstIdx, rankS, rankD,
                                                     offsS, offsD, ea, ew1, eb1,
                                                     hE, permInv, E_);

    for (int l = 0; l < 3; l++) {
        const float* hin   = (l == 0) ? x : tmp;
        const float* hroot = (l == 0) ? x : bufA;
        float* statsCur = statsR3 + (size_t)l * NREP * 32;
        const float* statsPrev = statsR3 + (size_t)(l - 1) * NREP * 32;
        k_Tmsg<<<(N + 15) / 16, 256, 0, stream>>>(
            hin, (l == 0) ? nullptr : statsPrev,
            (l == 0) ? nullptr : gam + (size_t)(l - 1) * 16,
            (l == 0) ? nullptr : bet + (size_t)(l - 1) * 16,
            bufA, ew2, eb2, hE, offsS, permInv, msg, N, (l == 0) ? 0 : 1);
        k_agg<<<(N + 15) / 16, 256, 0, stream>>>(hroot, msg, offsD,
                                                 root + (size_t)l * 256, cb + (size_t)l * 16,
                                                 tmp, statsCur, N);
    }

    k_readout<<<Gc, 512, 0, stream>>>(tmp, statsR3 + (size_t)2 * NREP * 32,
                                      gam + 32, bet + 32, lens, f1w, f1b, f2w, f2b,
                                      outHidden, outPooled, outFc, outLsm, Gc, N);
}

// Round 15
// 282.236 us; speedup vs baseline: 1.1256x; 1.0664x over previous
//
#include <hip/hip_runtime.h>

#define D 16
#define EFD 8
#define NREP 64       // BN-stats replica buffers (breaks atomic same-line contention)
#define TSTRIDE 272   // Tt row: 256 T values + 16 bias; 272%32==16 -> benign aliasing

typedef unsigned short u16;
typedef unsigned int u32;

__device__ __forceinline__ u16 f2bf(float x) {          // round-to-nearest-even
    u32 u = __float_as_uint(x);
    u += 0x7fffu + ((u >> 16) & 1u);
    return (u16)(u >> 16);
}
__device__ __forceinline__ void unpack8(uint4 u, float* f) {
    f[0] = __uint_as_float(u.x << 16); f[1] = __uint_as_float(u.x & 0xffff0000u);
    f[2] = __uint_as_float(u.y << 16); f[3] = __uint_as_float(u.y & 0xffff0000u);
    f[4] = __uint_as_float(u.z << 16); f[5] = __uint_as_float(u.z & 0xffff0000u);
    f[6] = __uint_as_float(u.w << 16); f[7] = __uint_as_float(u.w & 0xffff0000u);
}

#if __has_builtin(__builtin_amdgcn_fdot2_f32_bf16)
typedef __attribute__((ext_vector_type(2))) __bf16 bf16x2;
__device__ __forceinline__ float dot2bf(u32 a, u32 b, float c) {
    union { u32 u; bf16x2 v; } ua, ub;
    ua.u = a; ub.u = b;
    return __builtin_amdgcn_fdot2_f32_bf16(ua.v, ub.v, c, false);
}
#else
__device__ __forceinline__ float dot2bf(u32 a, u32 b, float c) {
    float f0 = __uint_as_float(a << 16), f1 = __uint_as_float(a & 0xffff0000u);
    float g0 = __uint_as_float(b << 16), g1 = __uint_as_float(b & 0xffff0000u);
    return c + f0 * g0 + f1 * g1;
}
#endif

// ---------------- zero scratch ----------------

__global__ void k_zero2(int* a, int na, float* b, int nb) {
    int i = blockIdx.x * 256 + threadIdx.x;
    if (i < na) a[i] = 0;
    if (i < nb) b[i] = 0.f;
}

// ---------------- rank: one atomic per edge per side ----------------

__global__ void k_rank2(const int* __restrict__ src, const int* __restrict__ dst,
                        int* __restrict__ cntS, int* __restrict__ cntD,
                        int* __restrict__ rankS, int* __restrict__ rankD, int E_) {
    int e = blockIdx.x * 256 + threadIdx.x;
    if (e < E_) {
        rankS[e] = atomicAdd(&cntS[src[e]], 1);
        rankD[e] = atomicAdd(&cntD[dst[e]], 1);
    }
}

// ---------------- scans over cntS|cntD ----------------

__global__ void k_scanA2(const int* __restrict__ cnt2, int* __restrict__ offs2,
                         int* __restrict__ bsum2, int n, int nScan) {
    __shared__ int s[1024];
    int half = blockIdx.x / nScan;
    int blk  = blockIdx.x % nScan;
    const int* c = cnt2 + (size_t)half * n;
    int* of = offs2 + (size_t)half * (n + 1);
    int* bs = bsum2 + half * 64;
    int i = blk * 1024 + threadIdx.x;
    int v = (i < n) ? c[i] : 0;
    s[threadIdx.x] = v;
    __syncthreads();
    for (int d = 1; d < 1024; d <<= 1) {
        int t = (threadIdx.x >= d) ? s[threadIdx.x - d] : 0;
        __syncthreads();
        s[threadIdx.x] += t;
        __syncthreads();
    }
    int incl = s[threadIdx.x];
    if (i < n) of[i] = incl - v;
    if (threadIdx.x == 1023) bs[blk] = incl;
}

__global__ void k_scanC2(int* __restrict__ offs2, const int* __restrict__ bsum2,
                         int n, int nScan, int total) {
    __shared__ int s[64];
    int half = blockIdx.x / nScan;
    int blk  = blockIdx.x % nScan;
    int* of = offs2 + (size_t)half * (n + 1);
    const int* bs = bsum2 + half * 64;
    if (threadIdx.x < 64) s[threadIdx.x] = (threadIdx.x < nScan) ? bs[threadIdx.x] : 0;
    __syncthreads();
    if (threadIdx.x < 64) {
        for (int d = 1; d < 64; d <<= 1) {
            int t = (threadIdx.x >= d) ? s[threadIdx.x - d] : 0;
            __syncthreads();
            s[threadIdx.x] += t;
            __syncthreads();
        }
    } else {
        for (int d = 1; d < 64; d <<= 1) { __syncthreads(); __syncthreads(); }
    }
    int base = (blk == 0) ? 0 : s[blk - 1];
    int i = blk * 1024 + threadIdx.x;
    if (i < n) of[i] += base;
    else if (i == n) of[n] = total;
}

// ---------------- fused place + edge-MLP + permInv (hE bf16) ----------------

__global__ void k_place_he(const int* __restrict__ src, const int* __restrict__ dst,
                           const int* __restrict__ rankS, const int* __restrict__ rankD,
                           const int* __restrict__ offsS, const int* __restrict__ offsD,
                           const float* __restrict__ ea, const float* __restrict__ w1,
                           const float* __restrict__ b1,
                           u16* __restrict__ hE, int* __restrict__ permInv, int E_) {
    __shared__ float w1s[EFD * D];
    __shared__ float b1s[D];
    if (threadIdx.x < EFD * D) w1s[threadIdx.x] = w1[threadIdx.x];
    if (threadIdx.x < D) b1s[threadIdx.x] = b1[threadIdx.x];
    __syncthreads();
    int e = blockIdx.x * 256 + threadIdx.x;
    if (e >= E_) return;
    int p = offsS[src[e]] + rankS[e];
    int q = offsD[dst[e]] + rankD[e];
    permInv[p] = q;
    const float4* a4 = (const float4*)(ea + (size_t)e * EFD);
    float4 x0 = a4[0], x1 = a4[1];
    u32 pk[8];
#pragma unroll
    for (int v = 0; v < 8; v++) {
        float o0, o1;
#pragma unroll
        for (int h = 0; h < 2; h++) {
            int o = 2 * v + h;
            float u0 = x0.x * w1s[0 * D + o] + x0.y * w1s[1 * D + o]
                     + x0.z * w1s[2 * D + o] + x0.w * w1s[3 * D + o];
            float u1 = x1.x * w1s[4 * D + o] + x1.y * w1s[5 * D + o]
                     + x1.z * w1s[6 * D + o] + x1.w * w1s[7 * D + o];
            float t = tanhf(b1s[o] + u0 + u1);
            if (h == 0) o0 = t; else o1 = t;
        }
        pk[v] = (u32)f2bf(o0) | ((u32)f2bf(o1) << 16);
    }
    uint4* h8 = (uint4*)(hE + (size_t)p * D);
    h8[0] = make_uint4(pk[0], pk[1], pk[2], pk[3]);
    h8[1] = make_uint4(pk[4], pk[5], pk[6], pk[7]);
}

// ---------------- per-layer FUSED: BN + T-tile + messages (LDS-staged bulk hE, dot2 math) ----------------

#define SBSTRIDE 17   // uint4 stride per group buffer (bank-conflict padding)

__global__ void k_Tmsg(const float* __restrict__ hin, const float* __restrict__ statsPrev,
                       const float* __restrict__ gamma, const float* __restrict__ beta,
                       float* __restrict__ hout, const float* __restrict__ w2,
                       const float* __restrict__ b2, const u16* __restrict__ hE,
                       const int* __restrict__ offsS, const int* __restrict__ permInv,
                       u16* __restrict__ msg, int n, int useBN) {
    __shared__ float hs[16 * D];
    __shared__ float Tt[16 * TSTRIDE];
    __shared__ float sstats[32];
    __shared__ uint4 sbuf[4 * 2 * 4 * SBSTRIDE + 4];   // [wave][buf][group][17]
    int tid = threadIdx.x;
    int j = tid >> 4, o = tid & 15;
    int w = tid >> 6, jj = j & 3;
    int base = blockIdx.x * 16;
    int node = base + j;
    float fn = (float)n;
    int p0 = 0, p1 = 0;
    if (node < n) { p0 = offsS[node]; p1 = offsS[node + 1]; }
    int deg = p1 - p0;
    int nCh = (deg + 7) >> 3;
    uint4* buf0 = &sbuf[((w * 2 + 0) * 4 + jj) * SBSTRIDE];
    uint4* buf1 = &sbuf[((w * 2 + 1) * 4 + jj) * SBSTRIDE];

    // chunk-0 prefetch (global latency hides under the T phase)
    uint4 regH = make_uint4(0, 0, 0, 0);
    int regQ = 0;
    if (deg > 0) {
        int pr = p0 + (o >> 1);
        int pc = (pr < p1) ? pr : p1 - 1;
        regH = ((const uint4*)(hE + (size_t)pc * D))[o & 1];
        if (o < 8) {
            int pq = p0 + o;
            regQ = permInv[(pq < p1) ? pq : p1 - 1];
        }
    }

    // per-thread weight columns in registers
    float w16[16], b16[16];
#pragma unroll
    for (int i = 0; i < 16; i++) w16[i] = w2[j * 256 + i * 16 + o];
#pragma unroll
    for (int i = 0; i < 16; i++) b16[i] = b2[i * 16 + o];
    if (useBN && tid < 32) {
        float a = 0.f;
#pragma unroll 8
        for (int r = 0; r < NREP; r++) a += statsPrev[r * 32 + tid];
        sstats[tid] = a;
    }
    __syncthreads();
    {   // stage h rows (apply BN+tanh of previous layer if needed)
        float hv = 0.f;
        if (node < n) {
            float xin = hin[(size_t)node * D + o];
            if (useBN) {
                float mu = sstats[o] / fn;
                float var = sstats[16 + o] / fn - mu * mu;
                hv = tanhf((xin - mu) * rsqrtf(var + 1e-5f) * gamma[o] + beta[o]);
                hout[(size_t)node * D + o] = hv;
            } else {
                hv = xin;
            }
        }
        hs[tid] = hv;
    }
    __syncthreads();
    {   // T-tile: broadcast b128 reads of hs + register FMAs (4-way trees)
        const float4* hs4 = (const float4*)hs;
#pragma unroll
        for (int nb = 0; nb < 16; nb++) {
            float4 h0 = hs4[nb * 4 + 0], h1 = hs4[nb * 4 + 1];
            float4 h2 = hs4[nb * 4 + 2], h3 = hs4[nb * 4 + 3];
            float q0 = h0.x * w16[0]  + h0.y * w16[1]  + h0.z * w16[2]  + h0.w * w16[3];
            float q1 = h1.x * w16[4]  + h1.y * w16[5]  + h1.z * w16[6]  + h1.w * w16[7];
            float q2 = h2.x * w16[8]  + h2.y * w16[9]  + h2.z * w16[10] + h2.w * w16[11];
            float q3 = h3.x * w16[12] + h3.y * w16[13] + h3.z * w16[14] + h3.w * w16[15];
            Tt[nb * TSTRIDE + tid] = (q0 + q1) + (q2 + q3);
        }
        float4 h0 = hs4[j * 4 + 0], h1 = hs4[j * 4 + 1];
        float4 h2 = hs4[j * 4 + 2], h3 = hs4[j * 4 + 3];
        float q0 = h0.x * b16[0]  + h0.y * b16[1]  + h0.z * b16[2]  + h0.w * b16[3];
        float q1 = h1.x * b16[4]  + h1.y * b16[5]  + h1.z * b16[6]  + h1.w * b16[7];
        float q2 = h2.x * b16[8]  + h2.y * b16[9]  + h2.z * b16[10] + h2.w * b16[11];
        float q3 = h3.x * b16[12] + h3.y * b16[13] + h3.z * b16[14] + h3.w * b16[15];
        Tt[j * TSTRIDE + 256 + o] = (q0 + q1) + (q2 + q3);
    }
    __syncthreads();
    if (node < n && deg > 0) {   // message phase: chunked LDS-staged degree loop, dot2 math
        float tb = Tt[j * TSTRIDE + 256 + o];
        u32 trp[8];              // tr packed as bf16 pairs (feature 2h low, 2h+1 high)
#pragma unroll
        for (int h = 0; h < 8; h++) {
            float t0 = Tt[j * TSTRIDE + (2 * h) * 16 + o];
            float t1 = Tt[j * TSTRIDE + (2 * h + 1) * 16 + o];
            trp[h] = (u32)f2bf(t0) | ((u32)f2bf(t1) << 16);
        }
        buf0[o] = regH;                      // stage chunk 0
        for (int c = 0; c < nCh; c++) {
            uint4* cur = (c & 1) ? buf1 : buf0;
            uint4* nxt = (c & 1) ? buf0 : buf1;
            uint4 nH; int nQ = 0;
            if (c + 1 < nCh) {               // issue next chunk's global loads now
                int pr = p0 + (c + 1) * 8 + (o >> 1);
                int pc = (pr < p1) ? pr : p1 - 1;
                nH = ((const uint4*)(hE + (size_t)pc * D))[o & 1];
                if (o < 8) {
                    int pq = p0 + (c + 1) * 8 + o;
                    nQ = permInv[(pq < p1) ? pq : p1 - 1];
                }
            }
            int eMax = deg - c * 8;
            if (eMax > 8) eMax = 8;
            for (int i = 0; i < eMax; i++) {
                uint4 r0 = cur[2 * i], r1 = cur[2 * i + 1];   // broadcast reads
                int qe = __shfl(regQ, jj * 16 + i);
                float acc0 = tb, acc1 = 0.f;                  // 2 chains for ILP
                acc0 = dot2bf(r0.x, trp[0], acc0);
                acc1 = dot2bf(r0.y, trp[1], acc1);
                acc0 = dot2bf(r0.z, trp[2], acc0);
                acc1 = dot2bf(r0.w, trp[3], acc1);
                acc0 = dot2bf(r1.x, trp[4], acc0);
                acc1 = dot2bf(r1.y, trp[5], acc1);
                acc0 = dot2bf(r1.z, trp[6], acc0);
                acc1 = dot2bf(r1.w, trp[7], acc1);
                msg[(size_t)qe * D + o] = f2bf(acc0 + acc1);
            }
            if (c + 1 < nCh) {
                nxt[o] = nH;                 // stage next chunk
                regQ = nQ;
            }
        }
    }
}

// ---------------- per-layer: dst aggregation (sequential bf16 msg read) + root + BN stats ----------------

__global__ void k_agg(const float* __restrict__ h, const u16* __restrict__ msg,
                      const int* __restrict__ offsD, const float* __restrict__ root_l,
                      const float* __restrict__ cbias, float* __restrict__ hpre,
                      float* __restrict__ statsR, int n) {
    __shared__ float rootS[D * D];
    __shared__ float red[256], red2[256];
    if (threadIdx.x < D * D) rootS[threadIdx.x] = root_l[threadIdx.x];
    __syncthreads();
    int slot = threadIdx.x >> 4, o = threadIdx.x & 15;
    int node = blockIdx.x * 16 + slot;
    float acc = 0.f;
    if (node < n) {
        int p0 = offsD[node], p1 = offsD[node + 1];
        float sum = 0.f;
        int p = p0;
        for (; p + 8 <= p1; p += 8) {
            float a0 = __uint_as_float((u32)msg[(size_t)(p + 0) * D + o] << 16);
            float a1 = __uint_as_float((u32)msg[(size_t)(p + 1) * D + o] << 16);
            float a2 = __uint_as_float((u32)msg[(size_t)(p + 2) * D + o] << 16);
            float a3 = __uint_as_float((u32)msg[(size_t)(p + 3) * D + o] << 16);
            float a4 = __uint_as_float((u32)msg[(size_t)(p + 4) * D + o] << 16);
            float a5 = __uint_as_float((u32)msg[(size_t)(p + 5) * D + o] << 16);
            float a6 = __uint_as_float((u32)msg[(size_t)(p + 6) * D + o] << 16);
            float a7 = __uint_as_float((u32)msg[(size_t)(p + 7) * D + o] << 16);
            sum += ((a0 + a1) + (a2 + a3)) + ((a4 + a5) + (a6 + a7));
        }
        for (; p < p1; p++) sum += __uint_as_float((u32)msg[(size_t)p * D + o] << 16);
        float deg = (float)((p1 - p0) > 1 ? (p1 - p0) : 1);
        const float* hr = h + (size_t)node * D;
        float r0 = hr[0]  * rootS[0 * D + o]  + hr[1]  * rootS[1 * D + o]
                 + hr[2]  * rootS[2 * D + o]  + hr[3]  * rootS[3 * D + o];
        float r1 = hr[4]  * rootS[4 * D + o]  + hr[5]  * rootS[5 * D + o]
                 + hr[6]  * rootS[6 * D + o]  + hr[7]  * rootS[7 * D + o];
        float r2 = hr[8]  * rootS[8 * D + o]  + hr[9]  * rootS[9 * D + o]
                 + hr[10] * rootS[10 * D + o] + hr[11] * rootS[11 * D + o];
        float r3 = hr[12] * rootS[12 * D + o] + hr[13] * rootS[13 * D + o]
                 + hr[14] * rootS[14 * D + o] + hr[15] * rootS[15 * D + o];
        acc = sum / deg + cbias[o] + ((r0 + r1) + (r2 + r3));
        hpre[(size_t)node * D + o] = acc;
    }
    red[threadIdx.x] = acc;
    red2[threadIdx.x] = acc * acc;
    __syncthreads();
    for (int off = 128; off >= 16; off >>= 1) {
        if (threadIdx.x < off) {
            red[threadIdx.x] += red[threadIdx.x + off];
            red2[threadIdx.x] += red2[threadIdx.x + off];
        }
        __syncthreads();
    }
    if (threadIdx.x < 32) {
        float v = (threadIdx.x < 16) ? red[threadIdx.x] : red2[threadIdx.x - 16];
        atomicAdd(&statsR[(blockIdx.x & (NREP - 1)) * 32 + threadIdx.x], v);
    }
}

// ---------------- fused readout ----------------

__global__ void k_readout(const float* __restrict__ hpre, const float* __restrict__ statsR,
                          const float* __restrict__ gamma, const float* __restrict__ beta,
                          const int* __restrict__ lengths,
                          const float* __restrict__ w1, const float* __restrict__ b1,
                          const float* __restrict__ w2, const float* __restrict__ b2,
                          float* __restrict__ outHidden, float* __restrict__ outPooled,
                          float* __restrict__ fcOut, float* __restrict__ lsmOut,
                          int Gc, int n) {
    __shared__ int sl[512];
    __shared__ float sstats[32];
    int tid = threadIdx.x;
    int g = blockIdx.x;
    if (tid < 32) {
        float a = 0.f;
#pragma unroll 8
        for (int r = 0; r < NREP; r++) a += statsR[r * 32 + tid];
        sstats[tid] = a;
    }
    int v = (tid < Gc) ? lengths[tid] : 0;
    sl[tid] = v;
    __syncthreads();
    for (int d = 1; d < 512; d <<= 1) {
        int t = (tid >= d) ? sl[tid - d] : 0;
        __syncthreads();
        sl[tid] += t;
        __syncthreads();
    }
    int n1 = sl[g];
    int n0 = n1 - lengths[g];
    float fn = (float)n;
    int slot = tid >> 4, o = tid & 15;
    float mu = sstats[o] / fn;
    float var = sstats[16 + o] / fn - mu * mu;
    float rstd = rsqrtf(var + 1e-5f);
    float gm = gamma[o], bt = beta[o];
    float s = 0.f, mx = -3.402823466e38f, mn = 3.402823466e38f;
    for (int nd = n0 + slot; nd < n1; nd += 32) {
        float xin = hpre[(size_t)nd * D + o];
        float x = tanhf((xin - mu) * rstd * gm + bt);
        outHidden[(size_t)nd * D + o] = x;
        s += x;
        mx = fmaxf(mx, x);
        mn = fminf(mn, x);
    }
    __shared__ float rs[512], rmx[512], rmn[512];
    rs[tid] = s; rmx[tid] = mx; rmn[tid] = mn;
    __syncthreads();
    for (int off = 256; off >= 16; off >>= 1) {
        if (tid < off) {
            rs[tid] += rs[tid + off];
            rmx[tid] = fmaxf(rmx[tid], rmx[tid + off]);
            rmn[tid] = fminf(rmn[tid], rmn[tid + off]);
        }
        __syncthreads();
    }
    __shared__ float p64[64], t16[16], f10[10];
    __shared__ float mred, lred;
    if (tid < 16) {
        float cnt = fmaxf((float)(n1 - n0), 1.f);
        float sum = rs[tid];
        float* row = outPooled + (size_t)g * 64;
        float mean = sum / cnt;
        p64[tid] = mean;          row[tid] = mean;
        p64[16 + tid] = rmx[tid]; row[16 + tid] = rmx[tid];
        p64[32 + tid] = rmn[tid]; row[32 + tid] = rmn[tid];
        p64[48 + tid] = sum;      row[48 + tid] = sum;
    }
    __syncthreads();
    if (tid < 16) {
        float a = b1[tid];
        for (int k = 0; k < 64; k++) a += p64[k] * w1[k * 16 + tid];
        t16[tid] = tanhf(a);
    }
    __syncthreads();
    if (tid < 10) {
        float a = b2[tid];
        for (int oo = 0; oo < 16; oo++) a += t16[oo] * w2[oo * 10 + tid];
        f10[tid] = a;
        fcOut[(size_t)g * 10 + tid] = a;
    }
    __syncthreads();
    if (tid == 0) {
        float m = f10[0];
        for (int c = 1; c < 10; c++) m = fmaxf(m, f10[c]);
        float se = 0.f;
        for (int c = 0; c < 10; c++) se += expf(f10[c] - m);
        mred = m;
        lred = logf(se);
    }
    __syncthreads();
    if (tid < 10)
        lsmOut[(size_t)g * 10 + tid] = f10[tid] - mred - lred;
}

// ---------------- host ----------------

extern "C" void kernel_launch(void* const* d_in, const int* in_sizes, int n_in,
                              void* d_out, int out_size, void* d_ws, size_t ws_size,
                              hipStream_t stream) {
    const float* x    = (const float*)d_in[0];
    const float* ea   = (const float*)d_in[1];
    const float* ew1  = (const float*)d_in[2];
    const float* eb1  = (const float*)d_in[3];
    const float* ew2  = (const float*)d_in[4];
    const float* eb2  = (const float*)d_in[5];
    const float* root = (const float*)d_in[6];
    const float* cb   = (const float*)d_in[7];
    const float* gam  = (const float*)d_in[8];
    const float* bet  = (const float*)d_in[9];
    const float* f1w  = (const float*)d_in[10];
    const float* f1b  = (const float*)d_in[11];
    const float* f2w  = (const float*)d_in[12];
    const float* f2b  = (const float*)d_in[13];
    const int* eidx   = (const int*)d_in[14];
    const int* lens   = (const int*)d_in[15];

    int N  = in_sizes[0] / D;
    int E_ = in_sizes[1] / EFD;
    int Gc = in_sizes[15];
    const int* srcIdx = eidx;
    const int* dstIdx = eidx + E_;

    float* outHidden = (float*)d_out;
    float* outPooled = outHidden + (size_t)N * D;
    float* outFc     = outPooled + (size_t)Gc * 4 * D;
    float* outLsm    = outFc + (size_t)Gc * 10;

    char* wsp = (char*)d_ws;
    size_t off = 0;
    auto alloc = [&](size_t bytes) -> void* {
        void* p = wsp + off;
        off = (off + bytes + 255) & ~(size_t)255;
        return p;
    };
    int*   cnt2    = (int*)alloc((size_t)2 * N * 4);
    int*   offs2   = (int*)alloc((size_t)2 * (N + 1) * 4);
    int*   bsum2   = (int*)alloc(128 * 4);
    int*   rankS   = (int*)alloc((size_t)E_ * 4);
    int*   rankD   = (int*)alloc((size_t)E_ * 4);
    int*   permInv = (int*)alloc((size_t)E_ * 4);
    u16*   hE      = (u16*)alloc((size_t)E_ * D * 2);
    u16*   msg     = (u16*)alloc((size_t)E_ * D * 2);
    float* bufA    = (float*)alloc((size_t)N * D * 4);
    float* tmp     = (float*)alloc((size_t)N * D * 4);
    float* statsR3 = (float*)alloc((size_t)3 * NREP * 32 * 4);

    int* offsS = offs2;
    int* offsD = offs2 + (N + 1);
    int nScan = (N + 1023) / 1024;

    k_zero2<<<(2 * N + 255) / 256, 256, 0, stream>>>(cnt2, 2 * N, statsR3, 3 * NREP * 32);
    k_rank2<<<(E_ + 255) / 256, 256, 0, stream>>>(srcIdx, dstIdx, cnt2, cnt2 + N,
                                                  rankS, rankD, E_);
    k_scanA2<<<2 * nScan, 1024, 0, stream>>>(cnt2, offs2, bsum2, N, nScan);
    k_scanC2<<<2 * nScan, 1024, 0, stream>>>(offs2, bsum2, N, nScan, E_);
    k_place_he<<<(E_ + 255) / 256, 256, 0, stream>>>(srcIdx, dstIdx, rankS, rankD,
                                                     offsS, offsD, ea, ew1, eb1,
                                                     hE, permInv, E_);

    for (int l = 0; l < 3; l++) {
        const float* hin   = (l == 0) ? x : tmp;
        const float* hroot = (l == 0) ? x : bufA;
        float* statsCur = statsR3 + (size_t)l * NREP * 32;
        const float* statsPrev = statsR3 + (size_t)(l - 1) * NREP * 32;
        k_Tmsg<<<(N + 15) / 16, 256, 0, stream>>>(
            hin, (l == 0) ? nullptr : statsPrev,
            (l == 0) ? nullptr : gam + (size_t)(l - 1) * 16,
            (l == 0) ? nullptr : bet + (size_t)(l - 1) * 16,
            bufA, ew2, eb2, hE, offsS, permInv, msg, N, (l == 0) ? 0 : 1);
        k_agg<<<(N + 15) / 16, 256, 0, stream>>>(hroot, msg, offsD,
                                                 root + (size_t)l * 256, cb + (size_t)l * 16,
                                                 tmp, statsCur, N);
    }

    k_readout<<<Gc, 512, 0, stream>>>(tmp, statsR3 + (size_t)2 * NREP * 32,
                                      gam + 32, bet + 32, lens, f1w, f1b, f2w, f2b,
                                      outHidden, outPooled, outFc, outLsm, Gc, N);
}